// Round 16
// baseline (406.439 us; speedup 1.0000x reference)
//
#include <hip/hip_runtime.h>
#include <cstdint>
#include <cstddef>

#define NB 16
#define NC 64
#define NN 512
#define NT 64
#define BT (NB*NT)              // 1024
#define NN2 (NN*NN)             // 262144
#define XSTRIDE_B (NC*NN*NT)    // 2097152
#define XSTRIDE_C (NN*NT)       // 32768
#define XT_ROW (BT*NC)          // 65536

typedef __attribute__((ext_vector_type(8))) short short8;
typedef __attribute__((ext_vector_type(4))) float f32x4;
typedef unsigned short ushort_t;
typedef unsigned int uint_t;

__device__ __forceinline__ ushort_t f2bf(float f) {
    uint_t u = __builtin_bit_cast(uint_t, f);
    u += 0x7FFFu + ((u >> 16) & 1u);
    return (ushort_t)(u >> 16);
}
__device__ __forceinline__ float bf2f(ushort_t u) {
    return __builtin_bit_cast(float, (uint_t)u << 16);
}
__device__ __forceinline__ void gl_lds16(const void* g, void* s) {
    __builtin_amdgcn_global_load_lds(
        (const __attribute__((address_space(1))) unsigned int*)g,
        (__attribute__((address_space(3))) unsigned int*)s, 16, 0, 0);
}
__device__ __forceinline__ void wait_vm(int n) {
    if (n == 3)      asm volatile("s_waitcnt vmcnt(3)" ::: "memory");
    else             asm volatile("s_waitcnt vmcnt(0)" ::: "memory");
}

// ---------------------------------------------------------------------------
// K0a: combined channel-mix matrices in bf16 MFMA B-fragment order.
// ---------------------------------------------------------------------------
__global__ void k_prep(const float* __restrict__ wf, const float* __restrict__ wb,
                       const float* __restrict__ alpha, ushort_t* __restrict__ Wcb) {
    int i = blockIdx.x * 256 + threadIdx.x;
    if (i >= 7 * 4096) return;
    float a = 1.f / (1.f + expf(-alpha[0]));
    int r = i >> 12, co = i & 4095;
    int c = co >> 6, o = co & 63;
    float v;
    if      (r == 0) v = wf[co] + wb[co];
    else if (r == 1) v = a * wf[4096 + co];
    else if (r == 2) v = a * wf[8192 + co];
    else if (r == 3) v = a * wb[4096 + co];
    else if (r == 4) v = a * wb[8192 + co];
    else if (r == 5) v = (1.f - a) * (wf[4096 + co] + wb[4096 + co]);
    else             v = (1.f - a) * (wf[8192 + co] + wb[8192 + co]);
    int chunk = ((c >> 5) << 2) | (o >> 4);
    int lane  = (((c >> 3) & 3) << 4) | (o & 15);
    int j     = c & 7;
    Wcb[r * 4096 + chunk * 512 + lane * 8 + j] = f2bf(v);
}

// ---------------------------------------------------------------------------
// K0b: P matrices fp32 -> bf16 in FRAGMENT-PACKED layout:
//   Apk[r][nt(32)][kc(16)][lane(64)][8]
// ---------------------------------------------------------------------------
__global__ void k_prepP(const float* __restrict__ Pf, const float* __restrict__ Pb,
                        const float* __restrict__ Aa, ushort_t* __restrict__ Apk) {
    int i = blockIdx.x * 256 + threadIdx.x;     // chunk id: 6*32*16*64 = 196608
    if (i >= 196608) return;
    int lane = i & 63, kc = (i >> 6) & 15, nt = (i >> 10) & 31, r = i >> 15;
    const float* base;
    if      (r == 0) base = Pf + NN2;
    else if (r == 1) base = Pf + 2 * NN2;
    else if (r == 2) base = Pb + NN2;
    else if (r == 3) base = Pb + 2 * NN2;
    else if (r == 4) base = Aa + NN2;
    else             base = Aa + 2 * NN2;
    int n = nt * 16 + (lane & 15);
    int k0 = kc * 32 + (lane >> 4) * 8;
    const float* src = base + (size_t)n * NN + k0;
    float4 v0 = ((const float4*)src)[0];
    float4 v1 = ((const float4*)src)[1];
    uint4 o;
    o.x = (uint_t)f2bf(v0.x) | ((uint_t)f2bf(v0.y) << 16);
    o.y = (uint_t)f2bf(v0.z) | ((uint_t)f2bf(v0.w) << 16);
    o.z = (uint_t)f2bf(v1.x) | ((uint_t)f2bf(v1.y) << 16);
    o.w = (uint_t)f2bf(v1.z) | ((uint_t)f2bf(v1.w) << 16);
    *(uint4*)(Apk + (size_t)i * 8) = o;
}

// ---------------------------------------------------------------------------
// K0c: TCN weights -> bf16 A-fragment order. 5 mats: Wf0,Wf1,Wg0,Wg1,Wsk.
// ---------------------------------------------------------------------------
__global__ void k_prepW(const float* __restrict__ fw, const float* __restrict__ gw,
                        const float* __restrict__ sw, ushort_t* __restrict__ Wt) {
    int i = blockIdx.x * 256 + threadIdx.x;
    if (i >= 5 * 4096) return;
    int mat = i >> 12, t = i & 4095;
    int chunk = t >> 9, l = (t >> 3) & 63, j = t & 7;
    int m = chunk >> 1, kb = chunk & 1;
    int o = m * 16 + (l & 15);
    int c = kb * 32 + ((l >> 4) << 3) + j;
    float v;
    if      (mat == 0) v = fw[o * 128 + c * 2 + 0];
    else if (mat == 1) v = fw[o * 128 + c * 2 + 1];
    else if (mat == 2) v = gw[o * 128 + c * 2 + 0];
    else if (mat == 3) v = gw[o * 128 + c * 2 + 1];
    else               v = sw[o * 64 + c];
    Wt[i] = f2bf(v);
}

// ---------------------------------------------------------------------------
// K1: gated TCN via MFMA (unchanged from round 4).
// ---------------------------------------------------------------------------
#define XS_P 72
__device__ __forceinline__ int swzA(int r, int c) {
    return r * XS_P + (c ^ (((r >> 4) & 3) << 3));
}
__global__ __launch_bounds__(256, 3) void k_tcn(
    const float* __restrict__ x,
    const ushort_t* __restrict__ Wt,
    const float* __restrict__ fb, const float* __restrict__ gb,
    const float* __restrict__ sb,
    float* __restrict__ skip_out, ushort_t* __restrict__ XTbf) {
    __shared__ __align__(16) ushort_t Xs[65 * XS_P];
    __shared__ __align__(16) ushort_t Os[64 * XS_P];

    int tx = threadIdx.x;
    int b = blockIdx.x >> 9, n = blockIdx.x & (NN - 1);

    {
        int c = tx >> 2, tq = tx & 3, t0 = tq * 16;
        const float* src = x + (size_t)b * XSTRIDE_B + (size_t)c * XSTRIDE_C
                             + (size_t)n * NT + t0;
        float4 v0 = ((const float4*)src)[0];
        float4 v1 = ((const float4*)src)[1];
        float4 v2 = ((const float4*)src)[2];
        float4 v3 = ((const float4*)src)[3];
        float vv[16] = {v0.x, v0.y, v0.z, v0.w, v1.x, v1.y, v1.z, v1.w,
                        v2.x, v2.y, v2.z, v2.w, v3.x, v3.y, v3.z, v3.w};
#pragma unroll
        for (int e = 0; e < 16; ++e) {
            int r = t0 + e + 1;
            Xs[swzA(r, c)] = f2bf(vv[e]);
        }
        if (tx < 8) ((uint4*)Xs)[tx] = (uint4){0, 0, 0, 0};   // row 0 (t=-1) = 0
    }
    __syncthreads();

    int w = tx >> 6, l = tx & 63, lr = l & 15, lg = l >> 4;

    short8 wf0[2], wf1[2], wg0[2], wg1[2], wsk[2];
#pragma unroll
    for (int kb = 0; kb < 2; ++kb) {
        int off = (w * 2 + kb) * 512 + l * 8;
        wf0[kb] = *(const short8*)(Wt + 0 * 4096 + off);
        wf1[kb] = *(const short8*)(Wt + 1 * 4096 + off);
        wg0[kb] = *(const short8*)(Wt + 2 * 4096 + off);
        wg1[kb] = *(const short8*)(Wt + 3 * 4096 + off);
        wsk[kb] = *(const short8*)(Wt + 4 * 4096 + off);
    }
    float fbv[4], gbv[4], sbv[4];
#pragma unroll
    for (int q = 0; q < 4; ++q) {
        int o = w * 16 + lg * 4 + q;
        fbv[q] = fb[o]; gbv[q] = gb[o]; sbv[q] = sb[o];
    }

#pragma unroll
    for (int tb = 0; tb < 4; ++tb) {
        short8 b0[2], b1[2];
#pragma unroll
        for (int kb = 0; kb < 2; ++kb) {
            int blk = kb * 4 + lg;
            int r1 = tb * 16 + lr + 1, r0 = tb * 16 + lr;
            b1[kb] = *(const short8*)&Xs[r1 * XS_P + (((blk ^ ((r1 >> 4) & 3)) << 3))];
            b0[kb] = *(const short8*)&Xs[r0 * XS_P + (((blk ^ ((r0 >> 4) & 3)) << 3))];
        }
        f32x4 aF = {fbv[0], fbv[1], fbv[2], fbv[3]};
        f32x4 aG = {gbv[0], gbv[1], gbv[2], gbv[3]};
        aF = __builtin_amdgcn_mfma_f32_16x16x32_bf16(wf0[0], b0[0], aF, 0, 0, 0);
        aF = __builtin_amdgcn_mfma_f32_16x16x32_bf16(wf0[1], b0[1], aF, 0, 0, 0);
        aF = __builtin_amdgcn_mfma_f32_16x16x32_bf16(wf1[0], b1[0], aF, 0, 0, 0);
        aF = __builtin_amdgcn_mfma_f32_16x16x32_bf16(wf1[1], b1[1], aF, 0, 0, 0);
        aG = __builtin_amdgcn_mfma_f32_16x16x32_bf16(wg0[0], b0[0], aG, 0, 0, 0);
        aG = __builtin_amdgcn_mfma_f32_16x16x32_bf16(wg0[1], b0[1], aG, 0, 0, 0);
        aG = __builtin_amdgcn_mfma_f32_16x16x32_bf16(wg1[0], b1[0], aG, 0, 0, 0);
        aG = __builtin_amdgcn_mfma_f32_16x16x32_bf16(wg1[1], b1[1], aG, 0, 0, 0);
        int t = tb * 16 + lr;
#pragma unroll
        for (int q = 0; q < 4; ++q) {
            float fo = tanhf(aF[q]);
            float go = 1.f / (1.f + expf(-aG[q]));
            int o = w * 16 + lg * 4 + q;
            Os[swzA(t, o)] = f2bf(fo * go);
        }
    }
    __syncthreads();

    float* skp = skip_out + (size_t)b * XSTRIDE_B + (size_t)n * NT;
#pragma unroll
    for (int tb = 0; tb < 4; ++tb) {
        int t = tb * 16 + lr;
        short8 ov[2];
#pragma unroll
        for (int kb = 0; kb < 2; ++kb) {
            int blk = kb * 4 + lg;
            ov[kb] = *(const short8*)&Os[t * XS_P + (((blk ^ ((t >> 4) & 3)) << 3))];
        }
        f32x4 aS = {sbv[0], sbv[1], sbv[2], sbv[3]};
        aS = __builtin_amdgcn_mfma_f32_16x16x32_bf16(wsk[0], ov[0], aS, 0, 0, 0);
        aS = __builtin_amdgcn_mfma_f32_16x16x32_bf16(wsk[1], ov[1], aS, 0, 0, 0);
#pragma unroll
        for (int q = 0; q < 4; ++q) {
            int o = w * 16 + lg * 4 + q;
            skp[(size_t)o * XSTRIDE_C + t] = aS[q];
        }
    }

    {
        int t = tx >> 2, cch = (tx & 3) * 16;
        ushort_t* dst = XTbf + (size_t)n * XT_ROW + (size_t)b * 4096 + t * 64 + cch;
        int rX = t + 1;
#pragma unroll
        for (int blk2 = 0; blk2 < 2; ++blk2) {
            int cb = (cch >> 3) + blk2;
            short8 xv = *(const short8*)&Xs[rX * XS_P + ((cb ^ ((rX >> 4) & 3)) << 3)];
            short8 ovv = *(const short8*)&Os[t * XS_P + ((cb ^ ((t >> 4) & 3)) << 3)];
            uint_t pk[4];
#pragma unroll
            for (int h = 0; h < 4; ++h) {
                float s0 = bf2f((ushort_t)xv[h * 2]) + bf2f((ushort_t)ovv[h * 2]);
                float s1 = bf2f((ushort_t)xv[h * 2 + 1]) + bf2f((ushort_t)ovv[h * 2 + 1]);
                pk[h] = (uint_t)f2bf(s0) | ((uint_t)f2bf(s1) << 16);
            }
            *(uint4*)(dst + blk2 * 8) = (uint4){pk[0], pk[1], pk[2], pk[3]};
        }
    }
}

// ---------------------------------------------------------------------------
// K1b: repack XTbf (j-major) -> Bpk[bt][kc(16)][f(4)][lane(64)][8] bf16.
// ---------------------------------------------------------------------------
__global__ __launch_bounds__(256) void k_tr(const ushort_t* __restrict__ XTbf,
                                            ushort_t* __restrict__ Bpk) {
    __shared__ ushort_t tile[32 * XS_P];
    int tx = threadIdx.x;
    int bt = blockIdx.x;
    int jj = tx >> 3, c8 = (tx & 7) * 8;
    int f = tx >> 6, lane = tx & 63, lg = lane >> 4, lr = lane & 15;
    for (int kc = 0; kc < 16; ++kc) {
        if (kc) __syncthreads();
        *(uint4*)&tile[jj * XS_P + c8] =
            *(const uint4*)(XTbf + (size_t)(kc * 32 + jj) * XT_ROW + bt * 64 + c8);
        __syncthreads();
        ushort_t vals[8];
#pragma unroll
        for (int e = 0; e < 8; ++e)
            vals[e] = tile[(lg * 8 + e) * XS_P + f * 16 + lr];
        uint4 o;
        o.x = (uint_t)vals[0] | ((uint_t)vals[1] << 16);
        o.y = (uint_t)vals[2] | ((uint_t)vals[3] << 16);
        o.z = (uint_t)vals[4] | ((uint_t)vals[5] << 16);
        o.w = (uint_t)vals[6] | ((uint_t)vals[7] << 16);
        *(uint4*)(Bpk + (size_t)bt * 32768 + kc * 2048 + tx * 8) = o;
    }
}

// ---------------------------------------------------------------------------
// K2: fused diffusion GCN. ROUND 16: 4-kc merged groups (48 MFMA per barrier,
//   only 4 barriers in the K-loop) with ring-8 B buffer (two 16KB halves).
//   Group g reads half (g&1), stages the OTHER half for group g+1 (disjoint
//   by construction; half overwritten only after the barrier that ended the
//   group that read it; stage completion forced by end-of-group vmcnt(3)).
//   A-regs stay 9 short8 (36 VGPR): aCur ping-ponged in place after phase-0
//   issues; aT1 holds k1 then reloads k3 after phase-1; aT2 holds k2.
// ---------------------------------------------------------------------------
__global__ __launch_bounds__(256, 4) void k_gcn(
    const ushort_t* __restrict__ Apk,   // [6][32][16][512] bf16 frag-packed
    const ushort_t* __restrict__ Bpk,   // [1024][16][2048] bf16 frag-packed
    const ushort_t* __restrict__ XTbf,  // [512][65536] bf16
    const ushort_t* __restrict__ Wcb,   // [7][4096] bf16 frag order
    const float* __restrict__ bias,
    ushort_t* __restrict__ G) {         // [512][65536] bf16
    // flat LDS: B ring 8 x 4KB = 32768 B.
    // epilogue aliases (rings dead): sC = [0,8192) ; sY = [8192,17408)
    __shared__ __align__(16) char smem[32768];

    int tx = threadIdx.x;
    int w = tx >> 6, l = tx & 63;
    int lr = l & 15, lg = l >> 4;
    int s = w >> 1, h = w & 1;          // n-slice, r-half

    // XCD chunk swizzle (bijective, 16384 % 8 == 0)
    int bid = (blockIdx.x & 7) * 2048 + (blockIdx.x >> 3);
    int bt = bid >> 4;
    int n0i = bid & 15;                 // n-tile id (32 rows each)
    int n0 = n0i << 5;

    f32x4 acc[3][4];
#pragma unroll
    for (int j = 0; j < 3; ++j)
#pragma unroll
        for (int f = 0; f < 4; ++f) acc[j][f] = (f32x4){0.f, 0.f, 0.f, 0.f};

    // A: r = h*3 + j, nt = n0i*2 + s; per-lane 16B contiguous (packed)
    const ushort_t* aBase = Apk + (size_t)(h * 3) * NN2
                                + (size_t)(n0i * 2 + s) * 8192 + l * 8;
    // B: wave w stages frag w; contiguous 1KB per stage
    const ushort_t* bSrc = Bpk + (size_t)bt * 32768 + w * 512 + l * 8;

    // ---- prologue: aCur <- A(0); stage kc 0..3 into half 0; full drain ----
    short8 aCur[3], aT1[3], aT2[3];
#pragma unroll
    for (int j = 0; j < 3; ++j) aCur[j] = *(const short8*)(aBase + (size_t)j * NN2);
#pragma unroll
    for (int d = 0; d < 4; ++d)
        gl_lds16(bSrc + d * 2048, smem + d * 4096 + w * 1024);
    wait_vm(0);
    __builtin_amdgcn_s_barrier();
    __builtin_amdgcn_sched_barrier(0);

#pragma unroll
    for (int g = 0; g < 4; ++g) {
        const int k0 = 4 * g;
        // top: in-group A loads (k1, k2) — consumed 1-2 phases later
#pragma unroll
        for (int j = 0; j < 3; ++j) {
            aT1[j] = *(const short8*)(aBase + (size_t)j * NN2 + (k0 + 1) * 512);
            aT2[j] = *(const short8*)(aBase + (size_t)j * NN2 + (k0 + 2) * 512);
        }
        // stage next group's 4 kc into the other half
        if (g < 3) {
#pragma unroll
            for (int d = 0; d < 4; ++d)
                gl_lds16(bSrc + (k0 + 4 + d) * 2048,
                         smem + ((k0 + 4 + d) & 7) * 4096 + w * 1024);
        }
        // ---- phase 0: kc k0 with aCur ----
        {
            const char* sBr = smem + ((k0 + 0) & 7) * 4096;
            short8 bv[4];
#pragma unroll
            for (int f = 0; f < 4; ++f)
                bv[f] = *(const short8*)(sBr + f * 1024 + l * 16);
            __builtin_amdgcn_s_setprio(1);
#pragma unroll
            for (int j = 0; j < 3; ++j)
#pragma unroll
                for (int f = 0; f < 4; ++f)
                    acc[j][f] = __builtin_amdgcn_mfma_f32_16x16x32_bf16(
                        aCur[j], bv[f], acc[j][f], 0, 0, 0);
            __builtin_amdgcn_s_setprio(0);
        }
        // aCur <- A(k0+4) (next group's k0) — stays in flight across barrier
        if (g < 3) {
#pragma unroll
            for (int j = 0; j < 3; ++j)
                aCur[j] = *(const short8*)(aBase + (size_t)j * NN2 + (k0 + 4) * 512);
        }
        // ---- phase 1: kc k0+1 with aT1 ----
        {
            const char* sBr = smem + ((k0 + 1) & 7) * 4096;
            short8 bv[4];
#pragma unroll
            for (int f = 0; f < 4; ++f)
                bv[f] = *(const short8*)(sBr + f * 1024 + l * 16);
            __builtin_amdgcn_s_setprio(1);
#pragma unroll
            for (int j = 0; j < 3; ++j)
#pragma unroll
                for (int f = 0; f < 4; ++f)
                    acc[j][f] = __builtin_amdgcn_mfma_f32_16x16x32_bf16(
                        aT1[j], bv[f], acc[j][f], 0, 0, 0);
            __builtin_amdgcn_s_setprio(0);
        }
        // aT1 <- A(k0+3) (consumed phase 3, ~2 phases of slack)
#pragma unroll
        for (int j = 0; j < 3; ++j)
            aT1[j] = *(const short8*)(aBase + (size_t)j * NN2 + (k0 + 3) * 512);
        // ---- phase 2: kc k0+2 with aT2 ----
        {
            const char* sBr = smem + ((k0 + 2) & 7) * 4096;
            short8 bv[4];
#pragma unroll
            for (int f = 0; f < 4; ++f)
                bv[f] = *(const short8*)(sBr + f * 1024 + l * 16);
            __builtin_amdgcn_s_setprio(1);
#pragma unroll
            for (int j = 0; j < 3; ++j)
#pragma unroll
                for (int f = 0; f < 4; ++f)
                    acc[j][f] = __builtin_amdgcn_mfma_f32_16x16x32_bf16(
                        aT2[j], bv[f], acc[j][f], 0, 0, 0);
            __builtin_amdgcn_s_setprio(0);
        }
        // ---- phase 3: kc k0+3 with aT1 (reloaded) ----
        {
            const char* sBr = smem + ((k0 + 3) & 7) * 4096;
            short8 bv[4];
#pragma unroll
            for (int f = 0; f < 4; ++f)
                bv[f] = *(const short8*)(sBr + f * 1024 + l * 16);
            __builtin_amdgcn_s_setprio(1);
#pragma unroll
            for (int j = 0; j < 3; ++j)
#pragma unroll
                for (int f = 0; f < 4; ++f)
                    acc[j][f] = __builtin_amdgcn_mfma_f32_16x16x32_bf16(
                        aT1[j], bv[f], acc[j][f], 0, 0, 0);
            __builtin_amdgcn_s_setprio(0);
        }
        // end-of-group: keep only next-k0's 3 A-loads in flight (forces the
        // 4 B-stages — issued before them — complete before the barrier).
        wait_vm(g < 3 ? 3 : 0);
        __builtin_amdgcn_s_barrier();
        __builtin_amdgcn_sched_barrier(0);
    }

    // ---- epilogue: per-wave partial channel mix (r8/r13-verified) ----
    float* sC = (float*)smem;                             // [2][4][64][4] = 8KB
    ushort_t* sYw = (ushort_t*)(smem + 8192) + w * 1152;  // 16*72 per wave

    f32x4 acc2[4];
#pragma unroll
    for (int fo = 0; fo < 4; ++fo) {
        float b = (h == 0) ? bias[fo * 16 + lr] : 0.f;
        acc2[fo] = (f32x4){b, b, b, b};
    }
    const ushort_t* wBase = Wcb + l * 8;

    if (h == 0) {   // X * Wc0 term
        const ushort_t* xs = XTbf + (size_t)(n0 + s * 16 + lr) * XT_ROW + bt * 64 + lg * 8;
        short8 ay0 = *(const short8*)(xs);
        short8 ay1 = *(const short8*)(xs + 32);
#pragma unroll
        for (int kh = 0; kh < 2; ++kh)
#pragma unroll
            for (int fo = 0; fo < 4; ++fo) {
                short8 wv = *(const short8*)(wBase + (kh * 4 + fo) * 512);
                acc2[fo] = __builtin_amdgcn_mfma_f32_16x16x32_bf16(
                    kh ? ay1 : ay0, wv, acc2[fo], 0, 0, 0);
            }
    }
#pragma unroll
    for (int j = 0; j < 3; ++j) {
        int wcIdx = (h == 0) ? (j + 1) : (j + 4);
        // repack Y_j (C/D layout -> A-frag layout) via wave-private LDS
#pragma unroll
        for (int f = 0; f < 4; ++f)
#pragma unroll
            for (int q = 0; q < 4; ++q)
                sYw[(lg * 4 + q) * 72 + f * 16 + lr] = f2bf(acc[j][f][q]);
        short8 ay0 = *(const short8*)(&sYw[lr * 72 + lg * 8]);
        short8 ay1 = *(const short8*)(&sYw[lr * 72 + 32 + lg * 8]);
#pragma unroll
        for (int kh = 0; kh < 2; ++kh)
#pragma unroll
            for (int fo = 0; fo < 4; ++fo) {
                short8 wv = *(const short8*)(wBase + wcIdx * 4096 + (kh * 4 + fo) * 512);
                acc2[fo] = __builtin_amdgcn_mfma_f32_16x16x32_bf16(
                    kh ? ay1 : ay0, wv, acc2[fo], 0, 0, 0);
            }
    }

    // ---- combine the two r-half partials (one barrier) ----
    if (h == 1) {
#pragma unroll
        for (int fo = 0; fo < 4; ++fo)
            *(f32x4*)&sC[(s * 4 + fo) * 256 + l * 4] = acc2[fo];
    }
    __syncthreads();
    if (h == 0) {
        ushort_t* gp = G + (size_t)(n0 + s * 16 + lg * 4) * XT_ROW + bt * 64 + lr;
#pragma unroll
        for (int fo = 0; fo < 4; ++fo) {
            f32x4 other = *(const f32x4*)&sC[(s * 4 + fo) * 256 + l * 4];
#pragma unroll
            for (int q = 0; q < 4; ++q)
                gp[(size_t)q * XT_ROW + fo * 16] = f2bf(acc2[fo][q] + other[q]);
        }
    }
}

// ---------------------------------------------------------------------------
// K3: LayerNorm over C + transpose to (B,C,N,T). G is bf16.
// ---------------------------------------------------------------------------
__global__ __launch_bounds__(256) void k_ln_t(
    const ushort_t* __restrict__ G,
    const float* __restrict__ gamma, const float* __restrict__ beta,
    float* __restrict__ xout) {
    __shared__ float sT[64 * 65];
    __shared__ float sMu[64], sRs[64];
    __shared__ float sS[64 * 4], sQ[64 * 4];

    int bid = blockIdx.x;
    int b = bid >> 9, n = bid & (NN - 1);
    int tx = threadIdx.x;
    const ushort_t* src = G + (size_t)n * XT_ROW + (size_t)b * (NT * NC);

#pragma unroll
    for (int u = 0; u < 2; ++u) {
        int fi = u * 256 + tx;
        uint4 v = ((const uint4*)src)[fi];
        int t = fi >> 3, c = (fi & 7) * 8;
        sT[t * 65 + c + 0] = bf2f((ushort_t)(v.x & 0xffff));
        sT[t * 65 + c + 1] = bf2f((ushort_t)(v.x >> 16));
        sT[t * 65 + c + 2] = bf2f((ushort_t)(v.y & 0xffff));
        sT[t * 65 + c + 3] = bf2f((ushort_t)(v.y >> 16));
        sT[t * 65 + c + 4] = bf2f((ushort_t)(v.z & 0xffff));
        sT[t * 65 + c + 5] = bf2f((ushort_t)(v.z >> 16));
        sT[t * 65 + c + 6] = bf2f((ushort_t)(v.w & 0xffff));
        sT[t * 65 + c + 7] = bf2f((ushort_t)(v.w >> 16));
    }
    __syncthreads();
    {
        int row = tx >> 2, seg = tx & 3;
        float s = 0.f, q = 0.f;
        for (int cc = 0; cc < 16; ++cc) {
            float v = sT[row * 65 + seg * 16 + cc];
            s += v; q += v * v;
        }
        sS[row * 4 + seg] = s; sQ[row * 4 + seg] = q;
    }
    __syncthreads();
    if (tx < 64) {
        float ss = sS[tx * 4] + sS[tx * 4 + 1] + sS[tx * 4 + 2] + sS[tx * 4 + 3];
        float qq = sQ[tx * 4] + sQ[tx * 4 + 1] + sQ[tx * 4 + 2] + sQ[tx * 4 + 3];
        float mu = ss * (1.f / 64.f);
        float var = qq * (1.f / 64.f) - mu * mu;
        sMu[tx] = mu; sRs[tx] = rsqrtf(var + 1e-5f);
    }
    __syncthreads();
    {
        int t = tx & 63, cg = (tx >> 6) * 16;
        float mu = sMu[t], rs = sRs[t];
        for (int cc = 0; cc < 16; ++cc) {
            int c = cg + cc;
            float v = (sT[t * 65 + c] - mu) * rs * gamma[c] + beta[c];
            xout[(size_t)b * XSTRIDE_B + (size_t)c * XSTRIDE_C + (size_t)n * NT + t] = v;
        }
    }
}

// ---------------------------------------------------------------------------
extern "C" void kernel_launch(void* const* d_in, const int* in_sizes, int n_in,
                              void* d_out, int out_size, void* d_ws, size_t ws_size,
                              hipStream_t stream) {
    const float* x     = (const float*)d_in[0];
    const float* Pf    = (const float*)d_in[1];
    const float* Pb    = (const float*)d_in[2];
    const float* Aa    = (const float*)d_in[3];
    const float* fw    = (const float*)d_in[4];
    const float* fb    = (const float*)d_in[5];
    const float* gw    = (const float*)d_in[6];
    const float* gb    = (const float*)d_in[7];
    const float* sw    = (const float*)d_in[8];
    const float* sb    = (const float*)d_in[9];
    const float* wf    = (const float*)d_in[10];
    const float* wb    = (const float*)d_in[11];
    const float* gbias = (const float*)d_in[12];
    const float* lng   = (const float*)d_in[13];
    const float* lnb   = (const float*)d_in[14];
    const float* alpha = (const float*)d_in[15];

    float* xout = (float*)d_out;
    float* skip = (float*)d_out + (size_t)NB * NC * NN * NT;

    char* ws = (char*)d_ws;
    ushort_t* XTbf = (ushort_t*)(ws);                          // 67,108,864 B
    ushort_t* Bpk  = (ushort_t*)(ws + 67108864);               // 67,108,864 B
    ushort_t* Gb   = (ushort_t*)(ws + 134217728);              // 67,108,864 B
    ushort_t* Apk  = (ushort_t*)(ws + 201326592);              //  3,145,728 B
    ushort_t* Wcb  = (ushort_t*)(ws + 204472320);              //     57,344 B
    ushort_t* Wt   = (ushort_t*)(ws + 204537856);              //     40,960 B

    hipLaunchKernelGGL(k_prep, dim3(112), dim3(256), 0, stream, wf, wb, alpha, Wcb);
    hipLaunchKernelGGL(k_prepW, dim3(80), dim3(256), 0, stream, fw, gw, sw, Wt);
    hipLaunchKernelGGL(k_prepP, dim3(768), dim3(256), 0, stream, Pf, Pb, Aa, Apk);
    hipLaunchKernelGGL(k_tcn, dim3(NB * NN), dim3(256), 0, stream,
                       x, Wt, fb, gb, sb, skip, XTbf);
    hipLaunchKernelGGL(k_tr, dim3(1024), dim3(256), 0, stream, XTbf, Bpk);
    hipLaunchKernelGGL(k_gcn, dim3(16384), dim3(256), 0, stream,
                       Apk, Bpk, XTbf, Wcb, gbias, Gb);
    hipLaunchKernelGGL(k_ln_t, dim3(NB * NN), dim3(256), 0, stream, Gb, lng, lnb, xout);
}

// Round 17
// 389.834 us; speedup vs baseline: 1.0426x; 1.0426x over previous
//
#include <hip/hip_runtime.h>
#include <cstdint>
#include <cstddef>

#define NB 16
#define NC 64
#define NN 512
#define NT 64
#define BT (NB*NT)              // 1024
#define NN2 (NN*NN)             // 262144
#define XSTRIDE_B (NC*NN*NT)    // 2097152
#define XSTRIDE_C (NN*NT)       // 32768
#define XT_ROW (BT*NC)          // 65536

typedef __attribute__((ext_vector_type(8))) short short8;
typedef __attribute__((ext_vector_type(4))) float f32x4;
typedef unsigned short ushort_t;
typedef unsigned int uint_t;

__device__ __forceinline__ ushort_t f2bf(float f) {
    uint_t u = __builtin_bit_cast(uint_t, f);
    u += 0x7FFFu + ((u >> 16) & 1u);
    return (ushort_t)(u >> 16);
}
__device__ __forceinline__ float bf2f(ushort_t u) {
    return __builtin_bit_cast(float, (uint_t)u << 16);
}
__device__ __forceinline__ void gl_lds16(const void* g, void* s) {
    __builtin_amdgcn_global_load_lds(
        (const __attribute__((address_space(1))) unsigned int*)g,
        (__attribute__((address_space(3))) unsigned int*)s, 16, 0, 0);
}
// counted vmcnt with compile-time-foldable selector
__device__ __forceinline__ void wait_vm(int n) {
    if (n >= 8)      asm volatile("s_waitcnt vmcnt(8)" ::: "memory");
    else if (n == 6) asm volatile("s_waitcnt vmcnt(6)" ::: "memory");
    else if (n == 4) asm volatile("s_waitcnt vmcnt(4)" ::: "memory");
    else if (n == 2) asm volatile("s_waitcnt vmcnt(2)" ::: "memory");
    else             asm volatile("s_waitcnt vmcnt(0)" ::: "memory");
}

// ---------------------------------------------------------------------------
// K0a: combined channel-mix matrices in bf16 MFMA B-fragment order.
// ---------------------------------------------------------------------------
__global__ void k_prep(const float* __restrict__ wf, const float* __restrict__ wb,
                       const float* __restrict__ alpha, ushort_t* __restrict__ Wcb) {
    int i = blockIdx.x * 256 + threadIdx.x;
    if (i >= 7 * 4096) return;
    float a = 1.f / (1.f + expf(-alpha[0]));
    int r = i >> 12, co = i & 4095;
    int c = co >> 6, o = co & 63;
    float v;
    if      (r == 0) v = wf[co] + wb[co];
    else if (r == 1) v = a * wf[4096 + co];
    else if (r == 2) v = a * wf[8192 + co];
    else if (r == 3) v = a * wb[4096 + co];
    else if (r == 4) v = a * wb[8192 + co];
    else if (r == 5) v = (1.f - a) * (wf[4096 + co] + wb[4096 + co]);
    else             v = (1.f - a) * (wf[8192 + co] + wb[8192 + co]);
    int chunk = ((c >> 5) << 2) | (o >> 4);
    int lane  = (((c >> 3) & 3) << 4) | (o & 15);
    int j     = c & 7;
    Wcb[r * 4096 + chunk * 512 + lane * 8 + j] = f2bf(v);
}

// ---------------------------------------------------------------------------
// K0b: P matrices fp32 -> bf16 in FRAGMENT-PACKED layout:
//   Apk[r][nt(32)][kc(16)][lane(64)][8]
// ---------------------------------------------------------------------------
__global__ void k_prepP(const float* __restrict__ Pf, const float* __restrict__ Pb,
                        const float* __restrict__ Aa, ushort_t* __restrict__ Apk) {
    int i = blockIdx.x * 256 + threadIdx.x;     // chunk id: 6*32*16*64 = 196608
    if (i >= 196608) return;
    int lane = i & 63, kc = (i >> 6) & 15, nt = (i >> 10) & 31, r = i >> 15;
    const float* base;
    if      (r == 0) base = Pf + NN2;
    else if (r == 1) base = Pf + 2 * NN2;
    else if (r == 2) base = Pb + NN2;
    else if (r == 3) base = Pb + 2 * NN2;
    else if (r == 4) base = Aa + NN2;
    else             base = Aa + 2 * NN2;
    int n = nt * 16 + (lane & 15);
    int k0 = kc * 32 + (lane >> 4) * 8;
    const float* src = base + (size_t)n * NN + k0;
    float4 v0 = ((const float4*)src)[0];
    float4 v1 = ((const float4*)src)[1];
    uint4 o;
    o.x = (uint_t)f2bf(v0.x) | ((uint_t)f2bf(v0.y) << 16);
    o.y = (uint_t)f2bf(v0.z) | ((uint_t)f2bf(v0.w) << 16);
    o.z = (uint_t)f2bf(v1.x) | ((uint_t)f2bf(v1.y) << 16);
    o.w = (uint_t)f2bf(v1.z) | ((uint_t)f2bf(v1.w) << 16);
    *(uint4*)(Apk + (size_t)i * 8) = o;
}

// ---------------------------------------------------------------------------
// K0c: TCN weights -> bf16 A-fragment order. 5 mats: Wf0,Wf1,Wg0,Wg1,Wsk.
// ---------------------------------------------------------------------------
__global__ void k_prepW(const float* __restrict__ fw, const float* __restrict__ gw,
                        const float* __restrict__ sw, ushort_t* __restrict__ Wt) {
    int i = blockIdx.x * 256 + threadIdx.x;
    if (i >= 5 * 4096) return;
    int mat = i >> 12, t = i & 4095;
    int chunk = t >> 9, l = (t >> 3) & 63, j = t & 7;
    int m = chunk >> 1, kb = chunk & 1;
    int o = m * 16 + (l & 15);
    int c = kb * 32 + ((l >> 4) << 3) + j;
    float v;
    if      (mat == 0) v = fw[o * 128 + c * 2 + 0];
    else if (mat == 1) v = fw[o * 128 + c * 2 + 1];
    else if (mat == 2) v = gw[o * 128 + c * 2 + 0];
    else if (mat == 3) v = gw[o * 128 + c * 2 + 1];
    else               v = sw[o * 64 + c];
    Wt[i] = f2bf(v);
}

// ---------------------------------------------------------------------------
// K1: gated TCN via MFMA (unchanged from round 4).
// ---------------------------------------------------------------------------
#define XS_P 72
__device__ __forceinline__ int swzA(int r, int c) {
    return r * XS_P + (c ^ (((r >> 4) & 3) << 3));
}
__global__ __launch_bounds__(256, 3) void k_tcn(
    const float* __restrict__ x,
    const ushort_t* __restrict__ Wt,
    const float* __restrict__ fb, const float* __restrict__ gb,
    const float* __restrict__ sb,
    float* __restrict__ skip_out, ushort_t* __restrict__ XTbf) {
    __shared__ __align__(16) ushort_t Xs[65 * XS_P];
    __shared__ __align__(16) ushort_t Os[64 * XS_P];

    int tx = threadIdx.x;
    int b = blockIdx.x >> 9, n = blockIdx.x & (NN - 1);

    {
        int c = tx >> 2, tq = tx & 3, t0 = tq * 16;
        const float* src = x + (size_t)b * XSTRIDE_B + (size_t)c * XSTRIDE_C
                             + (size_t)n * NT + t0;
        float4 v0 = ((const float4*)src)[0];
        float4 v1 = ((const float4*)src)[1];
        float4 v2 = ((const float4*)src)[2];
        float4 v3 = ((const float4*)src)[3];
        float vv[16] = {v0.x, v0.y, v0.z, v0.w, v1.x, v1.y, v1.z, v1.w,
                        v2.x, v2.y, v2.z, v2.w, v3.x, v3.y, v3.z, v3.w};
#pragma unroll
        for (int e = 0; e < 16; ++e) {
            int r = t0 + e + 1;
            Xs[swzA(r, c)] = f2bf(vv[e]);
        }
        if (tx < 8) ((uint4*)Xs)[tx] = (uint4){0, 0, 0, 0};   // row 0 (t=-1) = 0
    }
    __syncthreads();

    int w = tx >> 6, l = tx & 63, lr = l & 15, lg = l >> 4;

    short8 wf0[2], wf1[2], wg0[2], wg1[2], wsk[2];
#pragma unroll
    for (int kb = 0; kb < 2; ++kb) {
        int off = (w * 2 + kb) * 512 + l * 8;
        wf0[kb] = *(const short8*)(Wt + 0 * 4096 + off);
        wf1[kb] = *(const short8*)(Wt + 1 * 4096 + off);
        wg0[kb] = *(const short8*)(Wt + 2 * 4096 + off);
        wg1[kb] = *(const short8*)(Wt + 3 * 4096 + off);
        wsk[kb] = *(const short8*)(Wt + 4 * 4096 + off);
    }
    float fbv[4], gbv[4], sbv[4];
#pragma unroll
    for (int q = 0; q < 4; ++q) {
        int o = w * 16 + lg * 4 + q;
        fbv[q] = fb[o]; gbv[q] = gb[o]; sbv[q] = sb[o];
    }

#pragma unroll
    for (int tb = 0; tb < 4; ++tb) {
        short8 b0[2], b1[2];
#pragma unroll
        for (int kb = 0; kb < 2; ++kb) {
            int blk = kb * 4 + lg;
            int r1 = tb * 16 + lr + 1, r0 = tb * 16 + lr;
            b1[kb] = *(const short8*)&Xs[r1 * XS_P + (((blk ^ ((r1 >> 4) & 3)) << 3))];
            b0[kb] = *(const short8*)&Xs[r0 * XS_P + (((blk ^ ((r0 >> 4) & 3)) << 3))];
        }
        f32x4 aF = {fbv[0], fbv[1], fbv[2], fbv[3]};
        f32x4 aG = {gbv[0], gbv[1], gbv[2], gbv[3]};
        aF = __builtin_amdgcn_mfma_f32_16x16x32_bf16(wf0[0], b0[0], aF, 0, 0, 0);
        aF = __builtin_amdgcn_mfma_f32_16x16x32_bf16(wf0[1], b0[1], aF, 0, 0, 0);
        aF = __builtin_amdgcn_mfma_f32_16x16x32_bf16(wf1[0], b1[0], aF, 0, 0, 0);
        aF = __builtin_amdgcn_mfma_f32_16x16x32_bf16(wf1[1], b1[1], aF, 0, 0, 0);
        aG = __builtin_amdgcn_mfma_f32_16x16x32_bf16(wg0[0], b0[0], aG, 0, 0, 0);
        aG = __builtin_amdgcn_mfma_f32_16x16x32_bf16(wg0[1], b0[1], aG, 0, 0, 0);
        aG = __builtin_amdgcn_mfma_f32_16x16x32_bf16(wg1[0], b1[0], aG, 0, 0, 0);
        aG = __builtin_amdgcn_mfma_f32_16x16x32_bf16(wg1[1], b1[1], aG, 0, 0, 0);
        int t = tb * 16 + lr;
#pragma unroll
        for (int q = 0; q < 4; ++q) {
            float fo = tanhf(aF[q]);
            float go = 1.f / (1.f + expf(-aG[q]));
            int o = w * 16 + lg * 4 + q;
            Os[swzA(t, o)] = f2bf(fo * go);
        }
    }
    __syncthreads();

    float* skp = skip_out + (size_t)b * XSTRIDE_B + (size_t)n * NT;
#pragma unroll
    for (int tb = 0; tb < 4; ++tb) {
        int t = tb * 16 + lr;
        short8 ov[2];
#pragma unroll
        for (int kb = 0; kb < 2; ++kb) {
            int blk = kb * 4 + lg;
            ov[kb] = *(const short8*)&Os[t * XS_P + (((blk ^ ((t >> 4) & 3)) << 3))];
        }
        f32x4 aS = {sbv[0], sbv[1], sbv[2], sbv[3]};
        aS = __builtin_amdgcn_mfma_f32_16x16x32_bf16(wsk[0], ov[0], aS, 0, 0, 0);
        aS = __builtin_amdgcn_mfma_f32_16x16x32_bf16(wsk[1], ov[1], aS, 0, 0, 0);
#pragma unroll
        for (int q = 0; q < 4; ++q) {
            int o = w * 16 + lg * 4 + q;
            skp[(size_t)o * XSTRIDE_C + t] = aS[q];
        }
    }

    {
        int t = tx >> 2, cch = (tx & 3) * 16;
        ushort_t* dst = XTbf + (size_t)n * XT_ROW + (size_t)b * 4096 + t * 64 + cch;
        int rX = t + 1;
#pragma unroll
        for (int blk2 = 0; blk2 < 2; ++blk2) {
            int cb = (cch >> 3) + blk2;
            short8 xv = *(const short8*)&Xs[rX * XS_P + ((cb ^ ((rX >> 4) & 3)) << 3)];
            short8 ovv = *(const short8*)&Os[t * XS_P + ((cb ^ ((t >> 4) & 3)) << 3)];
            uint_t pk[4];
#pragma unroll
            for (int h = 0; h < 4; ++h) {
                float s0 = bf2f((ushort_t)xv[h * 2]) + bf2f((ushort_t)ovv[h * 2]);
                float s1 = bf2f((ushort_t)xv[h * 2 + 1]) + bf2f((ushort_t)ovv[h * 2 + 1]);
                pk[h] = (uint_t)f2bf(s0) | ((uint_t)f2bf(s1) << 16);
            }
            *(uint4*)(dst + blk2 * 8) = (uint4){pk[0], pk[1], pk[2], pk[3]};
        }
    }
}

// ---------------------------------------------------------------------------
// K1b: repack XTbf (j-major) -> Bpk[bt][kc(16)][f(4)][lane(64)][8] bf16.
// ---------------------------------------------------------------------------
__global__ __launch_bounds__(256) void k_tr(const ushort_t* __restrict__ XTbf,
                                            ushort_t* __restrict__ Bpk) {
    __shared__ ushort_t tile[32 * XS_P];
    int tx = threadIdx.x;
    int bt = blockIdx.x;
    int jj = tx >> 3, c8 = (tx & 7) * 8;
    int f = tx >> 6, lane = tx & 63, lg = lane >> 4, lr = lane & 15;
    for (int kc = 0; kc < 16; ++kc) {
        if (kc) __syncthreads();
        *(uint4*)&tile[jj * XS_P + c8] =
            *(const uint4*)(XTbf + (size_t)(kc * 32 + jj) * XT_ROW + bt * 64 + c8);
        __syncthreads();
        ushort_t vals[8];
#pragma unroll
        for (int e = 0; e < 8; ++e)
            vals[e] = tile[(lg * 8 + e) * XS_P + f * 16 + lr];
        uint4 o;
        o.x = (uint_t)vals[0] | ((uint_t)vals[1] << 16);
        o.y = (uint_t)vals[2] | ((uint_t)vals[3] << 16);
        o.z = (uint_t)vals[4] | ((uint_t)vals[5] << 16);
        o.w = (uint_t)vals[6] | ((uint_t)vals[7] << 16);
        *(uint4*)(Bpk + (size_t)bt * 32768 + kc * 2048 + tx * 8) = o;
    }
}

// ---------------------------------------------------------------------------
// K2: fused diffusion GCN. FINAL (= round 15 best): 2-kc merged phases
//   (24 MFMA per barrier, 8 barriers) with ring-6 B buffer; packed A/B;
//   XCD chunk swizzle; counted vmcnt; setprio; r8-verified split epilogue.
// ---------------------------------------------------------------------------
__global__ __launch_bounds__(256, 4) void k_gcn(
    const ushort_t* __restrict__ Apk,   // [6][32][16][512] bf16 frag-packed
    const ushort_t* __restrict__ Bpk,   // [1024][16][2048] bf16 frag-packed
    const ushort_t* __restrict__ XTbf,  // [512][65536] bf16
    const ushort_t* __restrict__ Wcb,   // [7][4096] bf16 frag order
    const float* __restrict__ bias,
    ushort_t* __restrict__ G) {         // [512][65536] bf16
    // flat LDS: B ring 6 x 4KB = 24576 B.
    // epilogue aliases (rings dead): sC = [0,8192) ; sY = [8192,12800)
    __shared__ __align__(16) char smem[24576];

    int tx = threadIdx.x;
    int w = tx >> 6, l = tx & 63;
    int lr = l & 15, lg = l >> 4;
    int s = w >> 1, h = w & 1;          // n-slice, r-half

    // XCD chunk swizzle (bijective, 16384 % 8 == 0)
    int bid = (blockIdx.x & 7) * 2048 + (blockIdx.x >> 3);
    int bt = bid >> 4;
    int n0i = bid & 15;                 // n-tile id (32 rows each)
    int n0 = n0i << 5;

    f32x4 acc[3][4];
#pragma unroll
    for (int j = 0; j < 3; ++j)
#pragma unroll
        for (int f = 0; f < 4; ++f) acc[j][f] = (f32x4){0.f, 0.f, 0.f, 0.f};

    // A: r = h*3 + j, nt = n0i*2 + s; per-lane 16B contiguous (packed)
    const ushort_t* aBase = Apk + (size_t)(h * 3) * NN2
                                + (size_t)(n0i * 2 + s) * 8192 + l * 8;
    // B: wave w stages frag w; contiguous 1KB per stage
    const ushort_t* bSrc = Bpk + (size_t)bt * 32768 + w * 512 + l * 8;

    // ---- prologue: aA0 <- A(kc0); stage kc 0..3 into slots 0..3.
    //      vmcnt(2): aA0 + stage0 + stage1 done; stage2,3 in flight. ----
    short8 aA0[3], aA1[3], aB[3];
#pragma unroll
    for (int j = 0; j < 3; ++j) aA0[j] = *(const short8*)(aBase + (size_t)j * NN2);
#pragma unroll
    for (int d = 0; d < 4; ++d)
        gl_lds16(bSrc + d * 2048, smem + d * 4096 + w * 1024);
    wait_vm(2);
    __builtin_amdgcn_s_barrier();
    __builtin_amdgcn_sched_barrier(0);

#pragma unroll
    for (int g = 0; g < 8; ++g) {
        const int k0 = 2 * g, k1 = 2 * g + 1;
        // (1) aB <- A(k1)  (consumed 2nd half of THIS group, ~400cy away)
#pragma unroll
        for (int j = 0; j < 3; ++j)
            aB[j] = *(const short8*)(aBase + (size_t)j * NN2 + k1 * 512);
        // (2) A(k0+2) -> ping-pong target (consumed next group)
        if (k0 + 2 < 16) {
            if ((g & 1) == 0) {
#pragma unroll
                for (int j = 0; j < 3; ++j)
                    aA1[j] = *(const short8*)(aBase + (size_t)j * NN2 + (k0 + 2) * 512);
            } else {
#pragma unroll
                for (int j = 0; j < 3; ++j)
                    aA0[j] = *(const short8*)(aBase + (size_t)j * NN2 + (k0 + 2) * 512);
            }
        }
        // (3) stage kc k0+4, k1+4 into ring slots
        if (k0 + 4 < 16)
            gl_lds16(bSrc + (k0 + 4) * 2048, smem + ((k0 + 4) % 6) * 4096 + w * 1024);
        if (k1 + 4 < 16)
            gl_lds16(bSrc + (k1 + 4) * 2048, smem + ((k1 + 4) % 6) * 4096 + w * 1024);

        // (4) phase A: kc k0 with aA (loaded last group)
        {
            const char* sBr = smem + (k0 % 6) * 4096;
            short8 bv[4];
#pragma unroll
            for (int f = 0; f < 4; ++f)
                bv[f] = *(const short8*)(sBr + f * 1024 + l * 16);
            const short8 a0 = (g & 1) ? aA1[0] : aA0[0];
            const short8 a1 = (g & 1) ? aA1[1] : aA0[1];
            const short8 a2 = (g & 1) ? aA1[2] : aA0[2];
            __builtin_amdgcn_s_setprio(1);
#pragma unroll
            for (int f = 0; f < 4; ++f)
                acc[0][f] = __builtin_amdgcn_mfma_f32_16x16x32_bf16(a0, bv[f], acc[0][f], 0, 0, 0);
#pragma unroll
            for (int f = 0; f < 4; ++f)
                acc[1][f] = __builtin_amdgcn_mfma_f32_16x16x32_bf16(a1, bv[f], acc[1][f], 0, 0, 0);
#pragma unroll
            for (int f = 0; f < 4; ++f)
                acc[2][f] = __builtin_amdgcn_mfma_f32_16x16x32_bf16(a2, bv[f], acc[2][f], 0, 0, 0);
            __builtin_amdgcn_s_setprio(0);
        }
        // (5) phase B: kc k1 with aB
        {
            const char* sBr = smem + (k1 % 6) * 4096;
            short8 bv[4];
#pragma unroll
            for (int f = 0; f < 4; ++f)
                bv[f] = *(const short8*)(sBr + f * 1024 + l * 16);
            __builtin_amdgcn_s_setprio(1);
#pragma unroll
            for (int f = 0; f < 4; ++f)
                acc[0][f] = __builtin_amdgcn_mfma_f32_16x16x32_bf16(aB[0], bv[f], acc[0][f], 0, 0, 0);
#pragma unroll
            for (int f = 0; f < 4; ++f)
                acc[1][f] = __builtin_amdgcn_mfma_f32_16x16x32_bf16(aB[1], bv[f], acc[1][f], 0, 0, 0);
#pragma unroll
            for (int f = 0; f < 4; ++f)
                acc[2][f] = __builtin_amdgcn_mfma_f32_16x16x32_bf16(aB[2], bv[f], acc[2][f], 0, 0, 0);
            __builtin_amdgcn_s_setprio(0);
        }
        // (6) end-of-group: vmcnt leaves only this group's in-flight ops
        //     g<=5: 3 aB + 3 aA-next + 2 stages = 8; g=6: 6; g=7: drain.
        wait_vm(g <= 5 ? 8 : (g == 6 ? 6 : 0));
        __builtin_amdgcn_s_barrier();
        __builtin_amdgcn_sched_barrier(0);
    }

    // ---- epilogue: per-wave partial channel mix (r8/r13-verified) ----
    float* sC = (float*)smem;                             // [2][4][64][4] = 8KB
    ushort_t* sYw = (ushort_t*)(smem + 8192) + w * 1152;  // 16*72 per wave

    f32x4 acc2[4];
#pragma unroll
    for (int fo = 0; fo < 4; ++fo) {
        float b = (h == 0) ? bias[fo * 16 + lr] : 0.f;
        acc2[fo] = (f32x4){b, b, b, b};
    }
    const ushort_t* wBase = Wcb + l * 8;

    if (h == 0) {   // X * Wc0 term
        const ushort_t* xs = XTbf + (size_t)(n0 + s * 16 + lr) * XT_ROW + bt * 64 + lg * 8;
        short8 ay0 = *(const short8*)(xs);
        short8 ay1 = *(const short8*)(xs + 32);
#pragma unroll
        for (int kh = 0; kh < 2; ++kh)
#pragma unroll
            for (int fo = 0; fo < 4; ++fo) {
                short8 wv = *(const short8*)(wBase + (kh * 4 + fo) * 512);
                acc2[fo] = __builtin_amdgcn_mfma_f32_16x16x32_bf16(
                    kh ? ay1 : ay0, wv, acc2[fo], 0, 0, 0);
            }
    }
#pragma unroll
    for (int j = 0; j < 3; ++j) {
        int wcIdx = (h == 0) ? (j + 1) : (j + 4);
        // repack Y_j (C/D layout -> A-frag layout) via wave-private LDS
#pragma unroll
        for (int f = 0; f < 4; ++f)
#pragma unroll
            for (int q = 0; q < 4; ++q)
                sYw[(lg * 4 + q) * 72 + f * 16 + lr] = f2bf(acc[j][f][q]);
        short8 ay0 = *(const short8*)(&sYw[lr * 72 + lg * 8]);
        short8 ay1 = *(const short8*)(&sYw[lr * 72 + 32 + lg * 8]);
#pragma unroll
        for (int kh = 0; kh < 2; ++kh)
#pragma unroll
            for (int fo = 0; fo < 4; ++fo) {
                short8 wv = *(const short8*)(wBase + wcIdx * 4096 + (kh * 4 + fo) * 512);
                acc2[fo] = __builtin_amdgcn_mfma_f32_16x16x32_bf16(
                    kh ? ay1 : ay0, wv, acc2[fo], 0, 0, 0);
            }
    }

    // ---- combine the two r-half partials (one barrier) ----
    if (h == 1) {
#pragma unroll
        for (int fo = 0; fo < 4; ++fo)
            *(f32x4*)&sC[(s * 4 + fo) * 256 + l * 4] = acc2[fo];
    }
    __syncthreads();
    if (h == 0) {
        ushort_t* gp = G + (size_t)(n0 + s * 16 + lg * 4) * XT_ROW + bt * 64 + lr;
#pragma unroll
        for (int fo = 0; fo < 4; ++fo) {
            f32x4 other = *(const f32x4*)&sC[(s * 4 + fo) * 256 + l * 4];
#pragma unroll
            for (int q = 0; q < 4; ++q)
                gp[(size_t)q * XT_ROW + fo * 16] = f2bf(acc2[fo][q] + other[q]);
        }
    }
}

// ---------------------------------------------------------------------------
// K3: LayerNorm over C + transpose to (B,C,N,T). G is bf16.
// ---------------------------------------------------------------------------
__global__ __launch_bounds__(256) void k_ln_t(
    const ushort_t* __restrict__ G,
    const float* __restrict__ gamma, const float* __restrict__ beta,
    float* __restrict__ xout) {
    __shared__ float sT[64 * 65];
    __shared__ float sMu[64], sRs[64];
    __shared__ float sS[64 * 4], sQ[64 * 4];

    int bid = blockIdx.x;
    int b = bid >> 9, n = bid & (NN - 1);
    int tx = threadIdx.x;
    const ushort_t* src = G + (size_t)n * XT_ROW + (size_t)b * (NT * NC);

#pragma unroll
    for (int u = 0; u < 2; ++u) {
        int fi = u * 256 + tx;
        uint4 v = ((const uint4*)src)[fi];
        int t = fi >> 3, c = (fi & 7) * 8;
        sT[t * 65 + c + 0] = bf2f((ushort_t)(v.x & 0xffff));
        sT[t * 65 + c + 1] = bf2f((ushort_t)(v.x >> 16));
        sT[t * 65 + c + 2] = bf2f((ushort_t)(v.y & 0xffff));
        sT[t * 65 + c + 3] = bf2f((ushort_t)(v.y >> 16));
        sT[t * 65 + c + 4] = bf2f((ushort_t)(v.z & 0xffff));
        sT[t * 65 + c + 5] = bf2f((ushort_t)(v.z >> 16));
        sT[t * 65 + c + 6] = bf2f((ushort_t)(v.w & 0xffff));
        sT[t * 65 + c + 7] = bf2f((ushort_t)(v.w >> 16));
    }
    __syncthreads();
    {
        int row = tx >> 2, seg = tx & 3;
        float s = 0.f, q = 0.f;
        for (int cc = 0; cc < 16; ++cc) {
            float v = sT[row * 65 + seg * 16 + cc];
            s += v; q += v * v;
        }
        sS[row * 4 + seg] = s; sQ[row * 4 + seg] = q;
    }
    __syncthreads();
    if (tx < 64) {
        float ss = sS[tx * 4] + sS[tx * 4 + 1] + sS[tx * 4 + 2] + sS[tx * 4 + 3];
        float qq = sQ[tx * 4] + sQ[tx * 4 + 1] + sQ[tx * 4 + 2] + sQ[tx * 4 + 3];
        float mu = ss * (1.f / 64.f);
        float var = qq * (1.f / 64.f) - mu * mu;
        sMu[tx] = mu; sRs[tx] = rsqrtf(var + 1e-5f);
    }
    __syncthreads();
    {
        int t = tx & 63, cg = (tx >> 6) * 16;
        float mu = sMu[t], rs = sRs[t];
        for (int cc = 0; cc < 16; ++cc) {
            int c = cg + cc;
            float v = (sT[t * 65 + c] - mu) * rs * gamma[c] + beta[c];
            xout[(size_t)b * XSTRIDE_B + (size_t)c * XSTRIDE_C + (size_t)n * NT + t] = v;
        }
    }
}

// ---------------------------------------------------------------------------
extern "C" void kernel_launch(void* const* d_in, const int* in_sizes, int n_in,
                              void* d_out, int out_size, void* d_ws, size_t ws_size,
                              hipStream_t stream) {
    const float* x     = (const float*)d_in[0];
    const float* Pf    = (const float*)d_in[1];
    const float* Pb    = (const float*)d_in[2];
    const float* Aa    = (const float*)d_in[3];
    const float* fw    = (const float*)d_in[4];
    const float* fb    = (const float*)d_in[5];
    const float* gw    = (const float*)d_in[6];
    const float* gb    = (const float*)d_in[7];
    const float* sw    = (const float*)d_in[8];
    const float* sb    = (const float*)d_in[9];
    const float* wf    = (const float*)d_in[10];
    const float* wb    = (const float*)d_in[11];
    const float* gbias = (const float*)d_in[12];
    const float* lng   = (const float*)d_in[13];
    const float* lnb   = (const float*)d_in[14];
    const float* alpha = (const float*)d_in[15];

    float* xout = (float*)d_out;
    float* skip = (float*)d_out + (size_t)NB * NC * NN * NT;

    char* ws = (char*)d_ws;
    ushort_t* XTbf = (ushort_t*)(ws);                          // 67,108,864 B
    ushort_t* Bpk  = (ushort_t*)(ws + 67108864);               // 67,108,864 B
    ushort_t* Gb   = (ushort_t*)(ws + 134217728);              // 67,108,864 B
    ushort_t* Apk  = (ushort_t*)(ws + 201326592);              //  3,145,728 B
    ushort_t* Wcb  = (ushort_t*)(ws + 204472320);              //     57,344 B
    ushort_t* Wt   = (ushort_t*)(ws + 204537856);              //     40,960 B

    hipLaunchKernelGGL(k_prep, dim3(112), dim3(256), 0, stream, wf, wb, alpha, Wcb);
    hipLaunchKernelGGL(k_prepW, dim3(80), dim3(256), 0, stream, fw, gw, sw, Wt);
    hipLaunchKernelGGL(k_prepP, dim3(768), dim3(256), 0, stream, Pf, Pb, Aa, Apk);
    hipLaunchKernelGGL(k_tcn, dim3(NB * NN), dim3(256), 0, stream,
                       x, Wt, fb, gb, sb, skip, XTbf);
    hipLaunchKernelGGL(k_tr, dim3(1024), dim3(256), 0, stream, XTbf, Bpk);
    hipLaunchKernelGGL(k_gcn, dim3(16384), dim3(256), 0, stream,
                       Apk, Bpk, XTbf, Wcb, gbias, Gb);
    hipLaunchKernelGGL(k_ln_t, dim3(NB * NN), dim3(256), 0, stream, Gb, lng, lnb, xout);
}